// Round 12
// baseline (174.636 us; speedup 1.0000x reference)
//
#include <hip/hip_runtime.h>
#include <hip/hip_bf16.h>
#include <cstdint>
#include <cstddef>

#define B_   16
#define N_   1024
#define C_   384
#define H_   6
#define DFF_ 1536
#define R_   16384   // B_*N_

typedef __attribute__((ext_vector_type(8))) __bf16 bf16x8;
typedef __attribute__((ext_vector_type(4))) float  f32x4;
typedef __attribute__((ext_vector_type(8))) unsigned short u16x8;
typedef __attribute__((ext_vector_type(4))) unsigned short u16x4;

__device__ __forceinline__ float bf2f(unsigned short u){
    unsigned int x = ((unsigned int)u) << 16;
    return __builtin_bit_cast(float, x);
}
__device__ __forceinline__ unsigned short f2bf(float f){
    return __builtin_bit_cast(unsigned short, __float2bfloat16(f));
}
__device__ __forceinline__ unsigned int cvt_pk_bf16(float a, float b){
    unsigned int r;
    asm("v_cvt_pk_bf16_f32 %0, %1, %2" : "=v"(r) : "v"(a), "v"(b));
    return r;   // lo = bf16(a), hi = bf16(b)
}
// raw v_exp_f32 (2^x). Args provably in [-45,0] -> no OCML range/denorm fixup needed.
__device__ __forceinline__ float fast_exp2(float x){
    float r;
    asm("v_exp_f32 %0, %1" : "=v"(r) : "v"(x));
    return r;
}
__device__ __forceinline__ void gload16(const void* g, void* l){
    __builtin_amdgcn_global_load_lds(
        (const __attribute__((address_space(1))) unsigned int*)g,
        (__attribute__((address_space(3))) unsigned int*)l, 16, 0, 0);
}
// exact-GELU via Abramowitz-Stegun 7.1.25 erf approx (|err| <= 2.5e-5)
__device__ __forceinline__ float gelu_f(float u){
    float z  = fabsf(u) * 0.70710678118654752f;
    float t  = __builtin_amdgcn_rcpf(1.0f + 0.47047f*z);
    float e  = __expf(-z*z);
    float p  = t*(0.3480242f + t*(-0.0958798f + t*0.7478556f));
    float er = 1.0f - p*e;                       // erf(z), z>=0
    return 0.5f*u*(1.0f + copysignf(er, u));
}
__device__ __forceinline__ float ldv(const float* p, size_t i){ return p[i]; }
__device__ __forceinline__ float ldv(const __hip_bfloat16* p, size_t i){ return __bfloat162float(p[i]); }

// ---------------- LN1 + all-weight fp32->bf16 convert, one launch ----------------
__global__ __launch_bounds__(256) void ln1_cvt_kernel(
    const float* __restrict__ x, const float* __restrict__ g,
    const float* __restrict__ b, __hip_bfloat16* __restrict__ out,
    const float* __restrict__ i0, __hip_bfloat16* __restrict__ o0, int n0,
    const float* __restrict__ i1, __hip_bfloat16* __restrict__ o1, int n1,
    const float* __restrict__ i2, __hip_bfloat16* __restrict__ o2, int n2,
    const float* __restrict__ i3, __hip_bfloat16* __restrict__ o3, int n3)
{
    if (blockIdx.x < 4096){
        const int lane = threadIdx.x & 63;
        const int wave = threadIdx.x >> 6;
        const int row  = blockIdx.x*4 + wave;
        const float* xr = x + (size_t)row*C_;
        float v[6];
        float s = 0.f;
        #pragma unroll
        for (int i=0;i<6;i++){ v[i] = xr[lane + i*64]; s += v[i]; }
        #pragma unroll
        for (int m=1;m<64;m<<=1) s += __shfl_xor(s, m);
        const float mean = s * (1.0f/C_);
        float sq = 0.f;
        #pragma unroll
        for (int i=0;i<6;i++){ float d = v[i]-mean; sq += d*d; }
        #pragma unroll
        for (int m=1;m<64;m<<=1) sq += __shfl_xor(sq, m);
        const float rstd = rsqrtf(sq*(1.0f/C_) + 1e-5f);
        #pragma unroll
        for (int i=0;i<6;i++){
            int c = lane + i*64;
            out[(size_t)row*C_ + c] = __float2bfloat16((v[i]-mean)*rstd*g[c] + b[c]);
        }
    } else {
        const int total = n0+n1+n2+n3;
        for (int i = (blockIdx.x-4096)*blockDim.x + threadIdx.x; i < total; i += 1024*blockDim.x){
            int k = i;
            if (k < n0){ o0[k] = __float2bfloat16(i0[k]); continue; }
            k -= n0;
            if (k < n1){ o1[k] = __float2bfloat16(i1[k]); continue; }
            k -= n1;
            if (k < n2){ o2[k] = __float2bfloat16(i2[k]); continue; }
            k -= n2;
            o3[k] = __float2bfloat16(i3[k]);
        }
    }
}

// ---------------- LayerNorm: (fp32|bf16) in -> bf16 out ----------------
template<typename T>
__global__ __launch_bounds__(256) void ln_kernel(
    const T* __restrict__ x, const float* __restrict__ g,
    const float* __restrict__ b, __hip_bfloat16* __restrict__ out)
{
    const int lane = threadIdx.x & 63;
    const int wave = threadIdx.x >> 6;
    const int row  = blockIdx.x*4 + wave;
    const T* xr = x + (size_t)row*C_;
    float v[6];
    float s = 0.f;
    #pragma unroll
    for (int i=0;i<6;i++){ v[i] = ldv(xr, lane + i*64); s += v[i]; }
    #pragma unroll
    for (int m=1;m<64;m<<=1) s += __shfl_xor(s, m);
    const float mean = s * (1.0f/C_);
    float sq = 0.f;
    #pragma unroll
    for (int i=0;i<6;i++){ float d = v[i]-mean; sq += d*d; }
    #pragma unroll
    for (int m=1;m<64;m<<=1) sq += __shfl_xor(sq, m);
    const float rstd = rsqrtf(sq*(1.0f/C_) + 1e-5f);
    #pragma unroll
    for (int i=0;i<6;i++){
        int c = lane + i*64;
        out[(size_t)row*C_ + c] = __float2bfloat16((v[i]-mean)*rstd*g[c] + b[c]);
    }
}

enum { EPI_QKV=0, EPI_PROJ=1, EPI_FC1=2, EPI_FC2=3 };

// gemm_wres: RT=2 -- B panel resident (stage-once), 4 A-bands (QKV/proj best, R6/R9/R11)
template<int EPI, int NCOLS>   // NCOLS: 1152 (QKV) / 384 (proj)
__global__ __launch_bounds__(256, 2) void gemm_wres(
    const __hip_bfloat16* __restrict__ A,    // [16384, 384]
    const __hip_bfloat16* __restrict__ Wt,   // [NCOLS, 384]
    const float* __restrict__ bias,
    const float* __restrict__ resid,
    const float* __restrict__ gate,
    __hip_bfloat16* __restrict__ outb)
{
    constexpr int NB = NCOLS/64;             // col-blocks
    constexpr int G  = 24;                   // RT=2 tiles x 12 K-steps
    __shared__ __align__(16) unsigned short As[4][128*32];   // 32KB: 4 bands, wave-private 32rx32k
    __shared__ __align__(16) unsigned short Bs[64*384];      // 48KB: whole-K weight panel
    const int t = threadIdx.x;
    const int l = t & 63;
    const int w = t >> 6;
    const int X  = blockIdx.x & 7;
    const int j8 = blockIdx.x >> 3;
    const int rb = X*8 + j8 / NB;            // row-group 0..63 (256 rows each)
    const int cb = j8 % NB;

    #pragma unroll
    for (int j=0;j<12;j++){
        const int L     = (w*12 + j)*1024 + l*16;       // linear LDS byte (gload_lds HW rule)
        const int row   = L / 768;                      // B row 0..63
        const int cbyte = L - row*768;
        const int scol  = (cbyte ^ ((row&7)<<4)) >> 1;  // inverse-swizzled source col (elems)
        gload16(Wt + (size_t)(cb*64 + row)*384 + scol, (char*)&Bs[0] + L);
    }
    const int sgcol = (((l&3) - ((l>>3)&3)) & 3) * 8;
    const size_t arow0 = (size_t)rb*256 + w*32 + (l>>2);
    auto STAGEA = [&](int g){
        const int rt = g/12, s = g - rt*12;
        #pragma unroll
        for (int c=0;c<2;c++)
            gload16(A + (arow0 + rt*128 + c*16)*384 + s*32 + sgcol,
                    (char*)&As[g&3][0] + w*2048 + c*1024 + l*16);
    };
    STAGEA(0); STAGEA(1); STAGEA(2);
    asm volatile("s_waitcnt vmcnt(6)" ::: "memory");    // 12 B loads drained; 3 bands in flight
    __builtin_amdgcn_s_barrier();                        // the ONLY barrier

    #pragma unroll
    for (int rt=0; rt<2; ++rt){
        f32x4 acc[2][4];
        #pragma unroll
        for (int i=0;i<2;i++)
            #pragma unroll
            for (int jj=0;jj<4;jj++) acc[i][jj] = (f32x4){0.f,0.f,0.f,0.f};

        #pragma unroll
        for (int s=0; s<12; ++s){
            const int g = rt*12 + s;
            if (g <= G-3)      asm volatile("s_waitcnt vmcnt(4)" ::: "memory");
            else if (g == G-2) asm volatile("s_waitcnt vmcnt(2)" ::: "memory");
            else               asm volatile("s_waitcnt vmcnt(0)" ::: "memory");
            const char* as = (const char*)&As[g&3][0] + w*2048;
            bf16x8 af[2], bw[4];
            #pragma unroll
            for (int i=0;i<2;i++){
                const int r  = i*16 + (l&15);
                const int sl = ((l>>4) + ((r>>1)&3)) & 3;
                af[i] = *(const bf16x8*)(as + r*64 + sl*16);
            }
            #pragma unroll
            for (int i=0;i<4;i++){
                const int r = i*16 + (l&15);                  // B row (output col) 0..63
                bw[i] = *(const bf16x8*)((const char*)&Bs[0] + r*768
                             + ((s*64 + (l>>4)*16) ^ ((r&7)<<4)));
            }
            #pragma unroll
            for (int mi=0;mi<2;mi++)
                #pragma unroll
                for (int ni=0;ni<4;ni++)
                    acc[mi][ni] = __builtin_amdgcn_mfma_f32_16x16x32_bf16(af[mi], bw[ni], acc[mi][ni], 0,0,0);
            asm volatile("s_waitcnt lgkmcnt(0)" ::: "memory");
            if (g+3 < G) STAGEA(g+3);
        }
        const int rowBase = rb*256 + rt*128 + w*32;
        if constexpr (EPI==EPI_QKV){
            unsigned short* ob = (unsigned short*)outb;
            #pragma unroll
            for (int ni=0; ni<4; ni++){
                const int col = cb*64 + ni*16 + (l&15);
                const int p = col/384, rem = col - p*384;
                const int hh = rem>>6, d = rem&63;
                #pragma unroll
                for (int mi=0; mi<2; mi++){
                    const int row0 = rowBase + mi*16 + (l>>4)*4;
                    const int bb = row0>>10, n = row0&1023;
                    if (p==2){
                        u16x4 pk;
                        #pragma unroll
                        for (int jj=0;jj<4;jj++) pk[jj] = f2bf(acc[mi][ni][jj]);
                        *(u16x4*)(ob + (size_t)2*6291456 + ((size_t)(bb*H_+hh)*64 + d)*1024 + n) = pk;
                    } else {
                        #pragma unroll
                        for (int jj=0;jj<4;jj++)
                            ob[(((size_t)((p*16+bb)*6+hh))<<16) + ((size_t)(n+jj)<<6) + d] = f2bf(acc[mi][ni][jj]);
                    }
                }
            }
        } else {
            #pragma unroll
            for (int ni=0; ni<4; ni++){
                const int col = cb*64 + ni*16 + (l&15);
                #pragma unroll
                for (int mi=0; mi<2; mi++){
                    #pragma unroll
                    for (int jj=0;jj<4;jj++){
                        const int row = rowBase + mi*16 + (l>>4)*4 + jj;
                        const size_t idx = (size_t)row*NCOLS + col;
                        outb[idx] = __float2bfloat16(resid[idx] + acc[mi][ni][jj] + bias[col]); // EPI_PROJ
                    }
                }
            }
        }
    }
}

// ---------------- R12: deep-MLP wres -- 6-step B chunks + 7 A-bands (FC1, FC2) ----------------
// R11 FC2 counters: VALUBusy 7%, HBM 800GB/s, MfmaUtil 13% -> MLP-bound (Little's law:
// ~4-6 outstanding loads/wave caps BW at ~1-2 TB/s). Fix at constant 80KB LDS / 2 blocks:
// B chunk 24KB (6 K-steps) + 7 bands 56KB. Chunk length (6) <= band lead (6) means every
// band a chunk needs is already DRAINED at the chunk-entry barrier -> ZERO in-chunk vmcnt
// waits; 12 loads/wave in flight (2x R11). Boundary protocol = R11's race-fixed one:
// [own ds_reads retired by step-5 lgkmcnt(0)] -> barrier -> STAGEB(q+1) -> vmcnt(0) ->
// barrier. Band WAR: stage g+6 at step g overwrites buf (g-1)%7, reads retired at step
// g-1's lgkmcnt(0). Bands for chunk q+1 are all issued during chunk q (before boundary).
template<int EPI, int KK, int NCOLS>   // FC1: K=384,NCOLS=1536 ; FC2: K=1536,NCOLS=384
__global__ __launch_bounds__(256, 2) void gemm_wres7(
    const __hip_bfloat16* __restrict__ A,      // [16384, KK]
    const __hip_bfloat16* __restrict__ Wt,     // [NCOLS, KK]
    const float* __restrict__ bias,            // [NCOLS]
    const __hip_bfloat16* __restrict__ residb, // FC2: x1b [16384,384]
    const float* __restrict__ gate,            // FC1: gate_mlp
    __hip_bfloat16* __restrict__ outb,         // FC1 out
    float* __restrict__ outf)                  // FC2 out
{
    constexpr int NB     = NCOLS/64;           // col-blocks
    constexpr int NSTEPS = KK/32;              // 12 / 48
    constexpr int QC     = KK/192;             // 2 / 8 chunks of 6 steps
    __shared__ __align__(16) unsigned short As[7][128*32];   // 56KB: 7 wave-private bands
    __shared__ __align__(16) unsigned short Bs[64*192];      // 24KB: one 6-step B chunk
    const int t = threadIdx.x;
    const int l = t & 63;
    const int w = t >> 6;
    const int X  = blockIdx.x & 7;
    const int j8 = blockIdx.x >> 3;
    const int rb = X*16 + j8 / NB;             // row-block 0..127 (128 rows)
    const int cb = j8 % NB;

    auto STAGEB = [&](int q){                  // chunk q: K cols [q*192, q*192+191]
        #pragma unroll
        for (int j=0;j<6;j++){
            const int L     = (w*6 + j)*1024 + l*16;   // linear LDS byte
            const int row   = L / 384;                 // B row 0..63 (row stride 384B)
            const int cbyte = L - row*384;
            const int scol  = (cbyte ^ ((row&7)<<4)) >> 1;  // inverse-swizzled src col
            gload16(Wt + (size_t)(cb*64 + row)*KK + q*192 + scol, (char*)&Bs[0] + L);
        }
    };
    const int sgcol = (((l&3) - ((l>>3)&3)) & 3) * 8;
    const size_t arow0 = (size_t)rb*128 + w*32 + (l>>2);
    auto STAGEA = [&](int g, int buf){
        #pragma unroll
        for (int c=0;c<2;c++)
            gload16(A + (arow0 + c*16)*KK + g*32 + sgcol,
                    (char*)&As[buf][0] + w*2048 + c*1024 + l*16);
    };

    STAGEB(0);
    STAGEA(0,0); STAGEA(1,1); STAGEA(2,2); STAGEA(3,3); STAGEA(4,4); STAGEA(5,5);
    asm volatile("s_waitcnt vmcnt(0)" ::: "memory");
    __builtin_amdgcn_s_barrier();
    asm volatile("" ::: "memory");

    f32x4 acc[2][4];
    #pragma unroll
    for (int i=0;i<2;i++)
        #pragma unroll
        for (int jj=0;jj<4;jj++) acc[i][jj] = (f32x4){0.f,0.f,0.f,0.f};

    int bidx = 0;                              // band buffer of current step (g mod 7)
    for (int q=0; q<QC; ++q){
        #pragma unroll
        for (int s=0; s<6; ++s){
            const int g = q*6 + s;
            const char* as = (const char*)&As[bidx][0] + w*2048;
            bf16x8 af[2], bw[4];
            #pragma unroll
            for (int i=0;i<2;i++){
                const int r  = i*16 + (l&15);          // local band row 0..31
                const int sl = ((l>>4) + ((r>>1)&3) ) & 3;
                af[i] = *(const bf16x8*)(as + r*64 + sl*16);
            }
            #pragma unroll
            for (int i=0;i<4;i++){
                const int r = i*16 + (l&15);           // B row (output col) 0..63
                bw[i] = *(const bf16x8*)((const char*)&Bs[0] + r*384
                             + ((s*64 + (l>>4)*16) ^ ((r&7)<<4)));
            }
            #pragma unroll
            for (int mi=0;mi<2;mi++)
                #pragma unroll
                for (int ni=0;ni<4;ni++)
                    acc[mi][ni] = __builtin_amdgcn_mfma_f32_16x16x32_bf16(af[mi], bw[ni], acc[mi][ni], 0,0,0);
            asm volatile("s_waitcnt lgkmcnt(0)" ::: "memory");  // own ds_reads retired
            if (g+6 < NSTEPS){
                const int sb = (bidx == 0) ? 6 : bidx-1;        // (g+6)%7 == (g-1)%7
                STAGEA(g+6, sb);
            }
            bidx = (bidx+1 == 7) ? 0 : bidx+1;
        }
        if (q+1 < QC){
            __builtin_amdgcn_s_barrier();      // all waves done reading Bs chunk q
            asm volatile("" ::: "memory");
            STAGEB(q+1);
            asm volatile("s_waitcnt vmcnt(0)" ::: "memory");   // B(q+1) + in-flight bands landed
            __builtin_amdgcn_s_barrier();
            asm volatile("" ::: "memory");
        }
    }

    // ---- epilogue (after loop) ----
    const int rowBase = rb*128 + w*32;
    if constexpr (EPI==EPI_FC1){
        #pragma unroll
        for (int ni=0; ni<4; ni++){
            const int col = cb*64 + ni*16 + (l&15);
            #pragma unroll
            for (int mi=0; mi<2; mi++){
                #pragma unroll
                for (int jj=0;jj<4;jj++){
                    const int row = rowBase + mi*16 + (l>>4)*4 + jj;
                    outb[(size_t)row*NCOLS + col] =
                        __float2bfloat16(gelu_f(acc[mi][ni][jj] + bias[col]) * gate[col]);
                }
            }
        }
    } else { // EPI_FC2: residual (bf16) + bias -> fp32 out
        const unsigned short* xb = (const unsigned short*)residb;
        #pragma unroll
        for (int ni=0; ni<4; ni++){
            const int col = cb*64 + ni*16 + (l&15);
            #pragma unroll
            for (int mi=0; mi<2; mi++){
                #pragma unroll
                for (int jj=0;jj<4;jj++){
                    const int row = rowBase + mi*16 + (l>>4)*4 + jj;
                    const size_t idx = (size_t)row*384 + col;
                    outf[idx] = bf2f(xb[idx]) + acc[mi][ni][jj] + bias[col];
                }
            }
        }
    }
}

// ---------------- MFMA flash attention, 3-buffer single-barrier pipeline (R12-best) ----------------
__global__ __launch_bounds__(256) void attn_mfma(
    const __hip_bfloat16* __restrict__ qg,   // [B,H,N,64]
    const __hip_bfloat16* __restrict__ kg,   // [B,H,N,64]
    const __hip_bfloat16* __restrict__ vtg,  // [B,H,64,N]
    const float* __restrict__ gate_h,
    __hip_bfloat16* __restrict__ og)         // [B,N,C]
{
    __shared__ __align__(16) unsigned short Ks [3][64*64];
    __shared__ __align__(16) unsigned short Vts[3][64*64];
    const int t = threadIdx.x;
    const int l = t & 63;
    const int w = t >> 6;
    const int X  = blockIdx.x & 7;
    const int j8 = blockIdx.x >> 3;          // 0..95
    const int bh = X*12 + (j8 >> 3);
    const int n0 = (j8 & 7) * 128;
    const int h  = bh % H_;
    const int b  = bh / H_;
    const unsigned short* qp  = (const unsigned short*)qg  + ((size_t)bh*N_ + n0 + w*32)*64;
    const unsigned short* kp  = (const unsigned short*)kg  + (size_t)bh*N_*64;
    const unsigned short* vtp = (const unsigned short*)vtg + (size_t)bh*64*N_;

    bf16x8 qf[2][2];
    #pragma unroll
    for (int mt=0;mt<2;mt++)
        #pragma unroll
        for (int dc=0;dc<2;dc++){
            u16x8 raw = *(const u16x8*)(qp + ((size_t)(mt*16 + (l&15)))*64 + dc*32 + (l>>4)*8);
            u16x8 sc;
            #pragma unroll
            for (int j=0;j<8;j++) sc[j] = f2bf(bf2f(raw[j]) * 0.1803368801111244f);
            qf[mt][dc] = __builtin_bit_cast(bf16x8, sc);
        }

    int qk_off[4][2], pv_off[2][4];
    #pragma unroll
    for (int t4=0;t4<4;t4++){
        const int i    = l & 15;
        const int row  = 8*(i>>2) + (i&3) + 4*(t4&1) + 32*(t4>>1);   // phys_k(t4, i)
        const int swzr = (row&3) | (((row>>3)&1)<<2);
        #pragma unroll
        for (int dc=0;dc<2;dc++)
            qk_off[t4][dc] = row*128 + ((dc*64 + (l>>4)*16) ^ (swzr<<4));
    }
    #pragma unroll
    for (int nt=0;nt<4;nt++){
        const int row  = nt*16 + (l&15);
        const int swzr = (row&3) | (((row>>3)&1)<<2);
        #pragma unroll
        for (int kc=0;kc<2;kc++)
            pv_off[kc][nt] = row*128 + ((kc*64 + (l>>4)*16) ^ (swzr<<4));
    }

    const int sr  = t >> 3;        // staging row 0..31 (and +32)
    const int sce = (t & 7) * 8;   // staging col (elements) before swizzle

    auto STAGE = [&](int buf, int kt){
        #pragma unroll
        for (int c=0;c<2;c++){
            const int r    = sr + c*32;
            const int swzr = (r&3) | (((r>>3)&1)<<2);
            const int col  = sce ^ (swzr<<3);           // inverse-swizzled global col
            gload16(kp  + ((size_t)(kt*64 + r))*64 + col, (char*)&Ks [buf][0] + (c*256 + t)*16);
            gload16(vtp + (size_t)r*N_ + kt*64 + col,     (char*)&Vts[buf][0] + (c*256 + t)*16);
        }
    };

    f32x4 o_acc[2][4];
    #pragma unroll
    for (int i=0;i<2;i++)
        #pragma unroll
        for (int jj=0;jj<4;jj++) o_acc[i][jj] = (f32x4){0.f,0.f,0.f,0.f};
    float rs_part[2] = {0.f, 0.f};   // per-lane partial denominators (k is lane-local)

    STAGE(0, 0);
    STAGE(1, 1);
    int cur = 0, stb = 2;
    for (int kt=0; kt<16; kt++){
        if (kt < 15) asm volatile("s_waitcnt vmcnt(4)" ::: "memory");
        else         asm volatile("s_waitcnt vmcnt(0)" ::: "memory");
        __builtin_amdgcn_s_barrier();
        asm volatile("" ::: "memory");
        if (kt < 14){
            STAGE(stb, kt+2);
            stb = (stb+1==3) ? 0 : stb+1;
        }
        const char* ks = (const char*)&Ks[cur][0];
        const char* vs = (const char*)&Vts[cur][0];

        f32x4 s_acc[4][2];
        #pragma unroll
        for (int i=0;i<4;i++)
            #pragma unroll
            for (int jj=0;jj<2;jj++) s_acc[i][jj] = (f32x4){0.f,0.f,0.f,0.f};
        #pragma unroll
        for (int t4=0;t4<4;t4++)
            #pragma unroll
            for (int dc=0;dc<2;dc++){
                bf16x8 kf = *(const bf16x8*)(ks + qk_off[t4][dc]);
                #pragma unroll
                for (int mt=0;mt<2;mt++)
                    s_acc[t4][mt] = __builtin_amdgcn_mfma_f32_16x16x32_bf16(kf, qf[mt][dc], s_acc[t4][mt], 0,0,0);
            }
        #pragma unroll
        for (int mt=0;mt<2;mt++){
            float acc_s = 0.f;
            #pragma unroll
            for (int t4=0;t4<4;t4++){
                #pragma unroll
                for (int jj=0;jj<4;jj++){
                    float e = fast_exp2(s_acc[t4][mt][jj]);
                    s_acc[t4][mt][jj] = e;
                    acc_s += e;
                }
            }
            rs_part[mt] += acc_s;
        }
        #pragma unroll
        for (int kc=0;kc<2;kc++){
            union { unsigned int u[4]; bf16x8 v; } pu[2];
            #pragma unroll
            for (int mt=0;mt<2;mt++){
                pu[mt].u[0] = cvt_pk_bf16(s_acc[2*kc  ][mt][0], s_acc[2*kc  ][mt][1]);
                pu[mt].u[1] = cvt_pk_bf16(s_acc[2*kc  ][mt][2], s_acc[2*kc  ][mt][3]);
                pu[mt].u[2] = cvt_pk_bf16(s_acc[2*kc+1][mt][0], s_acc[2*kc+1][mt][1]);
                pu[mt].u[3] = cvt_pk_bf16(s_acc[2*kc+1][mt][2], s_acc[2*kc+1][mt][3]);
            }
            #pragma unroll
            for (int nt=0;nt<4;nt++){
                bf16x8 vf = *(const bf16x8*)(vs + pv_off[kc][nt]);
                #pragma unroll
                for (int mt=0;mt<2;mt++)
                    o_acc[mt][nt] = __builtin_amdgcn_mfma_f32_16x16x32_bf16(pu[mt].v, vf, o_acc[mt][nt], 0,0,0);
            }
        }
        cur = (cur+1==3) ? 0 : cur+1;
    }
    float rowsum[2];
    #pragma unroll
    for (int mt=0;mt<2;mt++){
        float rs = rs_part[mt];
        rs += __shfl_xor(rs, 16);
        rs += __shfl_xor(rs, 32);
        rowsum[mt] = rs;
    }
    const float gh = gate_h[h];
    float inv[2][4];
    #pragma unroll
    for (int mt=0;mt<2;mt++)
        #pragma unroll
        for (int r=0;r<4;r++)
            inv[mt][r] = gh / __shfl(rowsum[mt], (l>>4)*4 + r, 16);
    unsigned short* op = (unsigned short*)og + ((size_t)b*N_ + n0 + w*32)*C_ + h*64;
    #pragma unroll
    for (int mt=0;mt<2;mt++){
        #pragma unroll
        for (int r=0;r<4;r++){
            const int n = mt*16 + (l>>4)*4 + r;
            #pragma unroll
            for (int nt=0;nt<4;nt++)
                op[(size_t)n*C_ + nt*16 + (l&15)] = f2bf(o_acc[mt][nt][r]*inv[mt][r]);
        }
    }
}

// ---------------- launch ----------------
extern "C" void kernel_launch(void* const* d_in, const int* in_sizes, int n_in,
                              void* d_out, int out_size, void* d_ws, size_t ws_size,
                              hipStream_t stream)
{
    const float* x     = (const float*)d_in[0];
    const float* ln1g  = (const float*)d_in[1];
    const float* ln1b  = (const float*)d_in[2];
    const float* qkvw  = (const float*)d_in[3];
    const float* projw = (const float*)d_in[4];
    const float* projb = (const float*)d_in[5];
    const float* gateh = (const float*)d_in[6];
    const float* ln2g  = (const float*)d_in[7];
    const float* ln2b  = (const float*)d_in[8];
    const float* fc1w  = (const float*)d_in[9];
    const float* fc1b  = (const float*)d_in[10];
    const float* fc2w  = (const float*)d_in[11];
    const float* fc2b  = (const float*)d_in[12];
    const float* gatem = (const float*)d_in[13];
    float* out = (float*)d_out;

    char* ws = (char*)d_ws;
    __hip_bfloat16* h_buf = (__hip_bfloat16*)(ws + 0);          // 12.58MB  (h / h2)
    __hip_bfloat16* qkv   = (__hip_bfloat16*)(ws + 12582912);   // 37.75MB  (q,k,v^T)
    __hip_bfloat16* q_buf = qkv;
    __hip_bfloat16* k_buf = qkv + 6291456;
    __hip_bfloat16* vt_buf= qkv + 2*6291456;
    __hip_bfloat16* o_buf = (__hip_bfloat16*)(ws + 50331648);   // 12.58MB
    __hip_bfloat16* m_buf = (__hip_bfloat16*)(ws + 12582912);   // 50.33MB (reuses dead qkv+o)
    __hip_bfloat16* x1b   = (__hip_bfloat16*)(ws + 62914560);   // 12.58MB (bf16 residual)
    __hip_bfloat16* wqkv  = (__hip_bfloat16*)(ws + 88080384);
    __hip_bfloat16* wproj = (__hip_bfloat16*)(ws + 88965120);
    __hip_bfloat16* wfc1  = (__hip_bfloat16*)(ws + 89260032);
    __hip_bfloat16* wfc2  = (__hip_bfloat16*)(ws + 90439680);

    // LN1 + all weight converts, one launch (independent memory-bound tasks)
    ln1_cvt_kernel<<<5120, 256, 0, stream>>>(x, ln1g, ln1b, h_buf,
                                             qkvw, wqkv, 1152*384,
                                             projw, wproj, 384*384,
                                             fc1w, wfc1, 1536*384,
                                             fc2w, wfc2, 384*1536);

    // R12: FC1/FC2 -> deep-MLP wres7 (6-step chunks, 7 bands, zero in-chunk waits)
    gemm_wres<EPI_QKV,1152><<<1152, 256, 0, stream>>>(h_buf, wqkv, nullptr, nullptr, nullptr, qkv);
    attn_mfma<<<768, 256, 0, stream>>>(q_buf, k_buf, vt_buf, gateh, o_buf);
    gemm_wres<EPI_PROJ,384><<<384, 256, 0, stream>>>(o_buf, wproj, projb, x, nullptr, x1b);
    ln_kernel<__hip_bfloat16><<<4096, 256, 0, stream>>>(x1b, ln2g, ln2b, h_buf);
    gemm_wres7<EPI_FC1,384,1536><<<3072, 256, 0, stream>>>(h_buf, wfc1, fc1b, nullptr, gatem, m_buf, nullptr);
    gemm_wres7<EPI_FC2,1536,384><<<768, 256, 0, stream>>>(m_buf, wfc2, fc2b, x1b, nullptr, nullptr, out);
}

// Round 13
// 168.266 us; speedup vs baseline: 1.0379x; 1.0379x over previous
//
#include <hip/hip_runtime.h>
#include <hip/hip_bf16.h>
#include <cstdint>
#include <cstddef>

#define B_   16
#define N_   1024
#define C_   384
#define H_   6
#define DFF_ 1536
#define R_   16384   // B_*N_

typedef __attribute__((ext_vector_type(8))) __bf16 bf16x8;
typedef __attribute__((ext_vector_type(4))) float  f32x4;
typedef __attribute__((ext_vector_type(8))) unsigned short u16x8;
typedef __attribute__((ext_vector_type(4))) unsigned short u16x4;

__device__ __forceinline__ float bf2f(unsigned short u){
    unsigned int x = ((unsigned int)u) << 16;
    return __builtin_bit_cast(float, x);
}
__device__ __forceinline__ unsigned short f2bf(float f){
    return __builtin_bit_cast(unsigned short, __float2bfloat16(f));
}
__device__ __forceinline__ unsigned int cvt_pk_bf16(float a, float b){
    unsigned int r;
    asm("v_cvt_pk_bf16_f32 %0, %1, %2" : "=v"(r) : "v"(a), "v"(b));
    return r;   // lo = bf16(a), hi = bf16(b)
}
// raw v_exp_f32 (2^x). Args provably <= 0 -> no OCML range/denorm fixup needed.
__device__ __forceinline__ float fast_exp2(float x){
    float r;
    asm("v_exp_f32 %0, %1" : "=v"(r) : "v"(x));
    return r;
}
__device__ __forceinline__ void gload16(const void* g, void* l){
    __builtin_amdgcn_global_load_lds(
        (const __attribute__((address_space(1))) unsigned int*)g,
        (__attribute__((address_space(3))) unsigned int*)l, 16, 0, 0);
}
// exact-GELU via Abramowitz-Stegun 7.1.25 erf approx (|err| <= 2.5e-5)
// R13: e^{-z^2} via raw v_exp_f32 (arg = -z^2*log2e <= 0, always in range; 2^-big -> 0
// and erf -> 1, correct tail). Saves OCML __expf fixup VALU in FC1's 32-GELU epilogue.
__device__ __forceinline__ float gelu_f(float u){
    float z  = fabsf(u) * 0.70710678118654752f;
    float t  = __builtin_amdgcn_rcpf(1.0f + 0.47047f*z);
    float e  = fast_exp2(-z*z*1.4426950408889634f);
    float p  = t*(0.3480242f + t*(-0.0958798f + t*0.7478556f));
    float er = 1.0f - p*e;                       // erf(z), z>=0
    return 0.5f*u*(1.0f + copysignf(er, u));
}
__device__ __forceinline__ float ldv(const float* p, size_t i){ return p[i]; }
__device__ __forceinline__ float ldv(const __hip_bfloat16* p, size_t i){ return __bfloat162float(p[i]); }

// ---------------- LN1 + all-weight fp32->bf16 convert, one launch ----------------
__global__ __launch_bounds__(256) void ln1_cvt_kernel(
    const float* __restrict__ x, const float* __restrict__ g,
    const float* __restrict__ b, __hip_bfloat16* __restrict__ out,
    const float* __restrict__ i0, __hip_bfloat16* __restrict__ o0, int n0,
    const float* __restrict__ i1, __hip_bfloat16* __restrict__ o1, int n1,
    const float* __restrict__ i2, __hip_bfloat16* __restrict__ o2, int n2,
    const float* __restrict__ i3, __hip_bfloat16* __restrict__ o3, int n3)
{
    if (blockIdx.x < 4096){
        const int lane = threadIdx.x & 63;
        const int wave = threadIdx.x >> 6;
        const int row  = blockIdx.x*4 + wave;
        const float* xr = x + (size_t)row*C_;
        float v[6];
        float s = 0.f;
        #pragma unroll
        for (int i=0;i<6;i++){ v[i] = xr[lane + i*64]; s += v[i]; }
        #pragma unroll
        for (int m=1;m<64;m<<=1) s += __shfl_xor(s, m);
        const float mean = s * (1.0f/C_);
        float sq = 0.f;
        #pragma unroll
        for (int i=0;i<6;i++){ float d = v[i]-mean; sq += d*d; }
        #pragma unroll
        for (int m=1;m<64;m<<=1) sq += __shfl_xor(sq, m);
        const float rstd = rsqrtf(sq*(1.0f/C_) + 1e-5f);
        #pragma unroll
        for (int i=0;i<6;i++){
            int c = lane + i*64;
            out[(size_t)row*C_ + c] = __float2bfloat16((v[i]-mean)*rstd*g[c] + b[c]);
        }
    } else {
        const int total = n0+n1+n2+n3;
        for (int i = (blockIdx.x-4096)*blockDim.x + threadIdx.x; i < total; i += 1024*blockDim.x){
            int k = i;
            if (k < n0){ o0[k] = __float2bfloat16(i0[k]); continue; }
            k -= n0;
            if (k < n1){ o1[k] = __float2bfloat16(i1[k]); continue; }
            k -= n1;
            if (k < n2){ o2[k] = __float2bfloat16(i2[k]); continue; }
            k -= n2;
            o3[k] = __float2bfloat16(i3[k]);
        }
    }
}

// ---------------- LayerNorm: (fp32|bf16) in -> bf16 out ----------------
template<typename T>
__global__ __launch_bounds__(256) void ln_kernel(
    const T* __restrict__ x, const float* __restrict__ g,
    const float* __restrict__ b, __hip_bfloat16* __restrict__ out)
{
    const int lane = threadIdx.x & 63;
    const int wave = threadIdx.x >> 6;
    const int row  = blockIdx.x*4 + wave;
    const T* xr = x + (size_t)row*C_;
    float v[6];
    float s = 0.f;
    #pragma unroll
    for (int i=0;i<6;i++){ v[i] = ldv(xr, lane + i*64); s += v[i]; }
    #pragma unroll
    for (int m=1;m<64;m<<=1) s += __shfl_xor(s, m);
    const float mean = s * (1.0f/C_);
    float sq = 0.f;
    #pragma unroll
    for (int i=0;i<6;i++){ float d = v[i]-mean; sq += d*d; }
    #pragma unroll
    for (int m=1;m<64;m<<=1) sq += __shfl_xor(sq, m);
    const float rstd = rsqrtf(sq*(1.0f/C_) + 1e-5f);
    #pragma unroll
    for (int i=0;i<6;i++){
        int c = lane + i*64;
        out[(size_t)row*C_ + c] = __float2bfloat16((v[i]-mean)*rstd*g[c] + b[c]);
    }
}

enum { EPI_QKV=0, EPI_PROJ=1, EPI_FC1=2, EPI_FC2=3 };

// ---------------- per-op best-measured configs (R11 = session best, 169.3us) ----------------
// FC1/FC2 plateau DECLARED at ~52+-2us: 7 structural variants (barriers 96/8/4/0,
// prefetch lead 1/2/3/6, occupancy 8-16 waves, bank-conflicts 2.4M/0, MLP 4-12 loads)
// all land 52-55. 360 TF = structure-family ceiling for these skinny shapes.

// gemm_wres: RT=2 -- B panel resident (stage-once), 4 A-bands (QKV/proj best, R6/R9/R11)
template<int EPI, int NCOLS>   // NCOLS: 1152 (QKV) / 384 (proj)
__global__ __launch_bounds__(256, 2) void gemm_wres(
    const __hip_bfloat16* __restrict__ A,    // [16384, 384]
    const __hip_bfloat16* __restrict__ Wt,   // [NCOLS, 384]
    const float* __restrict__ bias,
    const float* __restrict__ resid,
    const float* __restrict__ gate,
    __hip_bfloat16* __restrict__ outb)
{
    constexpr int NB = NCOLS/64;             // col-blocks
    constexpr int G  = 24;                   // RT=2 tiles x 12 K-steps
    __shared__ __align__(16) unsigned short As[4][128*32];   // 32KB: 4 bands, wave-private 32rx32k
    __shared__ __align__(16) unsigned short Bs[64*384];      // 48KB: whole-K weight panel
    const int t = threadIdx.x;
    const int l = t & 63;
    const int w = t >> 6;
    const int X  = blockIdx.x & 7;
    const int j8 = blockIdx.x >> 3;
    const int rb = X*8 + j8 / NB;            // row-group 0..63 (256 rows each)
    const int cb = j8 % NB;

    #pragma unroll
    for (int j=0;j<12;j++){
        const int L     = (w*12 + j)*1024 + l*16;       // linear LDS byte (gload_lds HW rule)
        const int row   = L / 768;                      // B row 0..63
        const int cbyte = L - row*768;
        const int scol  = (cbyte ^ ((row&7)<<4)) >> 1;  // inverse-swizzled source col (elems)
        gload16(Wt + (size_t)(cb*64 + row)*384 + scol, (char*)&Bs[0] + L);
    }
    const int sgcol = (((l&3) - ((l>>3)&3)) & 3) * 8;
    const size_t arow0 = (size_t)rb*256 + w*32 + (l>>2);
    auto STAGEA = [&](int g){
        const int rt = g/12, s = g - rt*12;
        #pragma unroll
        for (int c=0;c<2;c++)
            gload16(A + (arow0 + rt*128 + c*16)*384 + s*32 + sgcol,
                    (char*)&As[g&3][0] + w*2048 + c*1024 + l*16);
    };
    STAGEA(0); STAGEA(1); STAGEA(2);
    asm volatile("s_waitcnt vmcnt(6)" ::: "memory");    // 12 B loads drained; 3 bands in flight
    __builtin_amdgcn_s_barrier();                        // the ONLY barrier

    #pragma unroll
    for (int rt=0; rt<2; ++rt){
        f32x4 acc[2][4];
        #pragma unroll
        for (int i=0;i<2;i++)
            #pragma unroll
            for (int jj=0;jj<4;jj++) acc[i][jj] = (f32x4){0.f,0.f,0.f,0.f};

        #pragma unroll
        for (int s=0; s<12; ++s){
            const int g = rt*12 + s;
            if (g <= G-3)      asm volatile("s_waitcnt vmcnt(4)" ::: "memory");
            else if (g == G-2) asm volatile("s_waitcnt vmcnt(2)" ::: "memory");
            else               asm volatile("s_waitcnt vmcnt(0)" ::: "memory");
            const char* as = (const char*)&As[g&3][0] + w*2048;
            bf16x8 af[2], bw[4];
            #pragma unroll
            for (int i=0;i<2;i++){
                const int r  = i*16 + (l&15);
                const int sl = ((l>>4) + ((r>>1)&3)) & 3;
                af[i] = *(const bf16x8*)(as + r*64 + sl*16);
            }
            #pragma unroll
            for (int i=0;i<4;i++){
                const int r = i*16 + (l&15);                  // B row (output col) 0..63
                bw[i] = *(const bf16x8*)((const char*)&Bs[0] + r*768
                             + ((s*64 + (l>>4)*16) ^ ((r&7)<<4)));
            }
            #pragma unroll
            for (int mi=0;mi<2;mi++)
                #pragma unroll
                for (int ni=0;ni<4;ni++)
                    acc[mi][ni] = __builtin_amdgcn_mfma_f32_16x16x32_bf16(af[mi], bw[ni], acc[mi][ni], 0,0,0);
            asm volatile("s_waitcnt lgkmcnt(0)" ::: "memory");
            if (g+3 < G) STAGEA(g+3);
        }
        const int rowBase = rb*256 + rt*128 + w*32;
        if constexpr (EPI==EPI_QKV){
            unsigned short* ob = (unsigned short*)outb;
            #pragma unroll
            for (int ni=0; ni<4; ni++){
                const int col = cb*64 + ni*16 + (l&15);
                const int p = col/384, rem = col - p*384;
                const int hh = rem>>6, d = rem&63;
                #pragma unroll
                for (int mi=0; mi<2; mi++){
                    const int row0 = rowBase + mi*16 + (l>>4)*4;
                    const int bb = row0>>10, n = row0&1023;
                    if (p==2){
                        u16x4 pk;
                        #pragma unroll
                        for (int jj=0;jj<4;jj++) pk[jj] = f2bf(acc[mi][ni][jj]);
                        *(u16x4*)(ob + (size_t)2*6291456 + ((size_t)(bb*H_+hh)*64 + d)*1024 + n) = pk;
                    } else {
                        #pragma unroll
                        for (int jj=0;jj<4;jj++)
                            ob[(((size_t)((p*16+bb)*6+hh))<<16) + ((size_t)(n+jj)<<6) + d] = f2bf(acc[mi][ni][jj]);
                    }
                }
            }
        } else {
            #pragma unroll
            for (int ni=0; ni<4; ni++){
                const int col = cb*64 + ni*16 + (l&15);
                #pragma unroll
                for (int mi=0; mi<2; mi++){
                    #pragma unroll
                    for (int jj=0;jj<4;jj++){
                        const int row = rowBase + mi*16 + (l>>4)*4 + jj;
                        const size_t idx = (size_t)row*NCOLS + col;
                        outb[idx] = __float2bfloat16(resid[idx] + acc[mi][ni][jj] + bias[col]); // EPI_PROJ
                    }
                }
            }
        }
    }
}

// gemm_wres4: RT=1 -- B panel resident, 4 A-bands deep lead, epilogue after loop (FC1 best)
template<int NCOLS>   // 1536 (FC1)
__global__ __launch_bounds__(256, 2) void gemm_wres4(
    const __hip_bfloat16* __restrict__ A,    // [16384, 384]
    const __hip_bfloat16* __restrict__ Wt,   // [NCOLS, 384]
    const float* __restrict__ bias,
    const float* __restrict__ gate,
    __hip_bfloat16* __restrict__ outb)
{
    constexpr int NB = NCOLS/64;             // col-blocks
    __shared__ __align__(16) unsigned short As[4][128*32];   // 32KB: 4 bands, wave-private 32rx32k
    __shared__ __align__(16) unsigned short Bs[64*384];      // 48KB: whole-K weight panel
    const int t = threadIdx.x;
    const int l = t & 63;
    const int w = t >> 6;
    const int X  = blockIdx.x & 7;
    const int j8 = blockIdx.x >> 3;
    const int rb = X*16 + j8 / NB;           // row-block 0..127 (128 rows each)
    const int cb = j8 % NB;

    #pragma unroll
    for (int j=0;j<12;j++){
        const int L     = (w*12 + j)*1024 + l*16;       // linear LDS byte (gload_lds HW rule)
        const int row   = L / 768;                      // B row 0..63
        const int cbyte = L - row*768;
        const int scol  = (cbyte ^ ((row&7)<<4)) >> 1;  // inverse-swizzled source col (elems)
        gload16(Wt + (size_t)(cb*64 + row)*384 + scol, (char*)&Bs[0] + L);
    }
    const int sgcol = (((l&3) - ((l>>3)&3)) & 3) * 8;
    const size_t arow0 = (size_t)rb*128 + w*32 + (l>>2);
    auto STAGEA = [&](int g){
        #pragma unroll
        for (int c=0;c<2;c++)
            gload16(A + (arow0 + c*16)*384 + g*32 + sgcol,
                    (char*)&As[g&3][0] + w*2048 + c*1024 + l*16);
    };
    STAGEA(0); STAGEA(1); STAGEA(2);
    asm volatile("s_waitcnt vmcnt(6)" ::: "memory");    // 12 B loads drained; 3 bands in flight
    __builtin_amdgcn_s_barrier();                        // the ONLY barrier

    f32x4 acc[2][4];
    #pragma unroll
    for (int i=0;i<2;i++)
        #pragma unroll
        for (int jj=0;jj<4;jj++) acc[i][jj] = (f32x4){0.f,0.f,0.f,0.f};

    #pragma unroll
    for (int s=0; s<12; ++s){
        if (s < 10)      asm volatile("s_waitcnt vmcnt(4)" ::: "memory");
        else if (s == 10) asm volatile("s_waitcnt vmcnt(2)" ::: "memory");
        else              asm volatile("s_waitcnt vmcnt(0)" ::: "memory");
        const char* as = (const char*)&As[s&3][0] + w*2048;
        bf16x8 af[2], bw[4];
        #pragma unroll
        for (int i=0;i<2;i++){
            const int r  = i*16 + (l&15);                 // local band row 0..31
            const int sl = ((l>>4) + ((r>>1)&3)) & 3;
            af[i] = *(const bf16x8*)(as + r*64 + sl*16);
        }
        #pragma unroll
        for (int i=0;i<4;i++){
            const int r = i*16 + (l&15);                  // B row (output col) 0..63
            bw[i] = *(const bf16x8*)((const char*)&Bs[0] + r*768
                         + ((s*64 + (l>>4)*16) ^ ((r&7)<<4)));
        }
        #pragma unroll
        for (int mi=0;mi<2;mi++)
            #pragma unroll
            for (int ni=0;ni<4;ni++)
                acc[mi][ni] = __builtin_amdgcn_mfma_f32_16x16x32_bf16(af[mi], bw[ni], acc[mi][ni], 0,0,0);
        asm volatile("s_waitcnt lgkmcnt(0)" ::: "memory");
        if (s+3 < 12) STAGEA(s+3);
    }

    // ---- epilogue (after loop; GELU via fast_exp2) ----
    const int rowBase = rb*128 + w*32;
    #pragma unroll
    for (int ni=0; ni<4; ni++){
        const int col = cb*64 + ni*16 + (l&15);
        #pragma unroll
        for (int mi=0; mi<2; mi++){
            #pragma unroll
            for (int jj=0;jj<4;jj++){
                const int row = rowBase + mi*16 + (l>>4)*4 + jj;
                const size_t idx = (size_t)row*NCOLS + col;
                outb[idx] = __float2bfloat16(gelu_f(acc[mi][ni][jj] + bias[col]) * gate[col]); // FC1
            }
        }
    }
}

// ---------------- FC2 wres, 4 K-chunked B panels (R11 race-fixed, FC2 best) ----------------
__global__ __launch_bounds__(256, 2) void gemm_wres_fc2(
    const __hip_bfloat16* __restrict__ A,      // m_buf [16384, 1536]
    const __hip_bfloat16* __restrict__ Wt,     // fc2w  [384, 1536]
    const float* __restrict__ bias,            // [384]
    const __hip_bfloat16* __restrict__ residb, // x1b [16384, 384]
    float* __restrict__ outf)                  // out [16384, 384] fp32
{
    constexpr int NB = 6;                    // 384/64 col-blocks
    __shared__ __align__(16) unsigned short As[4][128*32];   // 32KB: 4 bands
    __shared__ __align__(16) unsigned short Bs[64*384];      // 48KB: one K-chunk of B
    const int t = threadIdx.x;
    const int l = t & 63;
    const int w = t >> 6;
    const int X  = blockIdx.x & 7;
    const int j8 = blockIdx.x >> 3;          // 0..95
    const int rb = X*16 + j8 / NB;           // row-block 0..127
    const int cb = j8 % NB;

    auto STAGEB = [&](int q){                // chunk q: cols q*384..q*384+383 of each B row
        #pragma unroll
        for (int j=0;j<12;j++){
            const int L     = (w*12 + j)*1024 + l*16;
            const int row   = L / 768;
            const int cbyte = L - row*768;
            const int scol  = (cbyte ^ ((row&7)<<4)) >> 1;
            gload16(Wt + (size_t)(cb*64 + row)*1536 + q*384 + scol, (char*)&Bs[0] + L);
        }
    };
    const int sgcol = (((l&3) - ((l>>3)&3)) & 3) * 8;
    const size_t arow0 = (size_t)rb*128 + w*32 + (l>>2);
    auto STAGEA = [&](int g){                // global K-step g in [0,48)
        #pragma unroll
        for (int c=0;c<2;c++)
            gload16(A + (arow0 + c*16)*1536 + g*32 + sgcol,
                    (char*)&As[g&3][0] + w*2048 + c*1024 + l*16);
    };

    STAGEB(0);
    STAGEA(0); STAGEA(1); STAGEA(2);
    asm volatile("s_waitcnt vmcnt(0)" ::: "memory");
    __builtin_amdgcn_s_barrier();
    asm volatile("" ::: "memory");

    f32x4 acc[2][4];
    #pragma unroll
    for (int i=0;i<2;i++)
        #pragma unroll
        for (int jj=0;jj<4;jj++) acc[i][jj] = (f32x4){0.f,0.f,0.f,0.f};

    for (int q=0; q<4; ++q){
        if (q > 0){
            asm volatile("s_waitcnt vmcnt(0)" ::: "memory");   // B(q) + pre-issued bands landed
            __builtin_amdgcn_s_barrier();                       // panel ready for all waves
            asm volatile("" ::: "memory");
        }
        #pragma unroll
        for (int s=0; s<12; ++s){
            const int g = q*12 + s;
            if (s >= 3){                       // s<3: band pre-staged and drained at boundary
                if (g < 46)      asm volatile("s_waitcnt vmcnt(4)" ::: "memory");
                else if (g == 46) asm volatile("s_waitcnt vmcnt(2)" ::: "memory");
                else              asm volatile("s_waitcnt vmcnt(0)" ::: "memory");
            }
            const char* as = (const char*)&As[g&3][0] + w*2048;
            bf16x8 af[2], bw[4];
            #pragma unroll
            for (int i=0;i<2;i++){
                const int r  = i*16 + (l&15);
                const int sl = ((l>>4) + ((r>>1)&3)) & 3;
                af[i] = *(const bf16x8*)(as + r*64 + sl*16);
            }
            #pragma unroll
            for (int i=0;i<4;i++){
                const int r = i*16 + (l&15);
                bw[i] = *(const bf16x8*)((const char*)&Bs[0] + r*768
                             + ((s*64 + (l>>4)*16) ^ ((r&7)<<4)));
            }
            #pragma unroll
            for (int mi=0;mi<2;mi++)
                #pragma unroll
                for (int ni=0;ni<4;ni++)
                    acc[mi][ni] = __builtin_amdgcn_mfma_f32_16x16x32_bf16(af[mi], bw[ni], acc[mi][ni], 0,0,0);
            asm volatile("s_waitcnt lgkmcnt(0)" ::: "memory");  // own ds_reads retired before overwrites
            if (g+3 < 48) STAGEA(g+3);
        }
        if (q < 3){
            __builtin_amdgcn_s_barrier();      // RACE FIX: ALL waves done reading Bs chunk q
            asm volatile("" ::: "memory");
            STAGEB(q+1);                       // now safe to overwrite shared panel
        }
    }

    // ---- epilogue: residual (bf16) + bias -> fp32 out ----
    const int rowBase = rb*128 + w*32;
    const unsigned short* xb = (const unsigned short*)residb;
    #pragma unroll
    for (int ni=0; ni<4; ni++){
        const int col = cb*64 + ni*16 + (l&15);
        #pragma unroll
        for (int mi=0; mi<2; mi++){
            #pragma unroll
            for (int jj=0;jj<4;jj++){
                const int row = rowBase + mi*16 + (l>>4)*4 + jj;
                const size_t idx = (size_t)row*384 + col;
                outf[idx] = bf2f(xb[idx]) + acc[mi][ni][jj] + bias[col];
            }
        }
    }
}

// ---------------- MFMA flash attention, 3-buffer single-barrier pipeline ----------------
__global__ __launch_bounds__(256) void attn_mfma(
    const __hip_bfloat16* __restrict__ qg,   // [B,H,N,64]
    const __hip_bfloat16* __restrict__ kg,   // [B,H,N,64]
    const __hip_bfloat16* __restrict__ vtg,  // [B,H,64,N]
    const float* __restrict__ gate_h,
    __hip_bfloat16* __restrict__ og)         // [B,N,C]
{
    __shared__ __align__(16) unsigned short Ks [3][64*64];
    __shared__ __align__(16) unsigned short Vts[3][64*64];
    const int t = threadIdx.x;
    const int l = t & 63;
    const int w = t >> 6;
    const int X  = blockIdx.x & 7;
    const int j8 = blockIdx.x >> 3;          // 0..95
    const int bh = X*12 + (j8 >> 3);
    const int n0 = (j8 & 7) * 128;
    const int h  = bh % H_;
    const int b  = bh / H_;
    const unsigned short* qp  = (const unsigned short*)qg  + ((size_t)bh*N_ + n0 + w*32)*64;
    const unsigned short* kp  = (const unsigned short*)kg  + (size_t)bh*N_*64;
    const unsigned short* vtp = (const unsigned short*)vtg + (size_t)bh*64*N_;

    bf16x8 qf[2][2];
    #pragma unroll
    for (int mt=0;mt<2;mt++)
        #pragma unroll
        for (int dc=0;dc<2;dc++){
            u16x8 raw = *(const u16x8*)(qp + ((size_t)(mt*16 + (l&15)))*64 + dc*32 + (l>>4)*8);
            u16x8 sc;
            #pragma unroll
            for (int j=0;j<8;j++) sc[j] = f2bf(bf2f(raw[j]) * 0.1803368801111244f);
            qf[mt][dc] = __builtin_bit_cast(bf16x8, sc);
        }

    int qk_off[4][2], pv_off[2][4];
    #pragma unroll
    for (int t4=0;t4<4;t4++){
        const int i    = l & 15;
        const int row  = 8*(i>>2) + (i&3) + 4*(t4&1) + 32*(t4>>1);   // phys_k(t4, i)
        const int swzr = (row&3) | (((row>>3)&1)<<2);
        #pragma unroll
        for (int dc=0;dc<2;dc++)
            qk_off[t4][dc] = row*128 + ((dc*64 + (l>>4)*16) ^ (swzr<<4));
    }
    #pragma unroll
    for (int nt=0;nt<4;nt++){
        const int row  = nt*16 + (l&15);
        const int swzr = (row&3) | (((row>>3)&1)<<2);
        #pragma unroll
        for (int kc=0;kc<2;kc++)
            pv_off[kc][nt] = row*128 + ((kc*64 + (l>>4)*16) ^ (swzr<<4));
    }

    const int sr  = t >> 3;        // staging row 0..31 (and +32)
    const int sce = (t & 7) * 8;   // staging col (elements) before swizzle

    auto STAGE = [&](int buf, int kt){
        #pragma unroll
        for (int c=0;c<2;c++){
            const int r    = sr + c*32;
            const int swzr = (r&3) | (((r>>3)&1)<<2);
            const int col  = sce ^ (swzr<<3);           // inverse-swizzled global col
            gload16(kp  + ((size_t)(kt*64 + r))*64 + col, (char*)&Ks [buf][0] + (c*256 + t)*16);
            gload16(vtp + (size_t)r*N_ + kt*64 + col,     (char*)&Vts[buf][0] + (c*256 + t)*16);
        }
    };

    f32x4 o_acc[2][4];
    #pragma unroll
    for (int i=0;i<2;i++)
        #pragma unroll
        for (int jj=0;jj<4;jj++) o_acc[i][jj] = (f32x4){0.f,0.f,0.f,0.f};
    float rs_part[2] = {0.f, 0.f};   // per-lane partial denominators (k is lane-local)

    STAGE(0, 0);
    STAGE(1, 1);
    int cur = 0, stb = 2;
    for (int kt=0; kt<16; kt++){
        if (kt < 15) asm volatile("s_waitcnt vmcnt(4)" ::: "memory");
        else         asm volatile("s_waitcnt vmcnt(0)" ::: "memory");
        __builtin_amdgcn_s_barrier();
        asm volatile("" ::: "memory");
        if (kt < 14){
            STAGE(stb, kt+2);
            stb = (stb+1==3) ? 0 : stb+1;
        }
        const char* ks = (const char*)&Ks[cur][0];
        const char* vs = (const char*)&Vts[cur][0];

        f32x4 s_acc[4][2];
        #pragma unroll
        for (int i=0;i<4;i++)
            #pragma unroll
            for (int jj=0;jj<2;jj++) s_acc[i][jj] = (f32x4){0.f,0.f,0.f,0.f};
        #pragma unroll
        for (int t4=0;t4<4;t4++)
            #pragma unroll
            for (int dc=0;dc<2;dc++){
                bf16x8 kf = *(const bf16x8*)(ks + qk_off[t4][dc]);
                #pragma unroll
                for (int mt=0;mt<2;mt++)
                    s_acc[t4][mt] = __builtin_amdgcn_mfma_f32_16x16x32_bf16(kf, qf[mt][dc], s_acc[t4][mt], 0,0,0);
            }
        #pragma unroll
        for (int mt=0;mt<2;mt++){
            float acc_s = 0.f;
            #pragma unroll
            for (int t4=0;t4<4;t4++){
                #pragma unroll
                for (int jj=0;jj<4;jj++){
                    float e = fast_exp2(s_acc[t4][mt][jj]);
                    s_acc[t4][mt][jj] = e;
                    acc_s += e;
                }
            }
            rs_part[mt] += acc_s;
        }
        #pragma unroll
        for (int kc=0;kc<2;kc++){
            union { unsigned int u[4]; bf16x8 v; } pu[2];
            #pragma unroll
            for (int mt=0;mt<2;mt++){
                pu[mt].u[0] = cvt_pk_bf16(s_acc[2*kc  ][mt][0], s_acc[2*kc  ][mt][1]);
                pu[mt].u[1] = cvt_pk_bf16(s_acc[2*kc  ][mt][2], s_acc[2*kc  ][mt][3]);
                pu[mt].u[2] = cvt_pk_bf16(s_acc[2*kc+1][mt][0], s_acc[2*kc+1][mt][1]);
                pu[mt].u[3] = cvt_pk_bf16(s_acc[2*kc+1][mt][2], s_acc[2*kc+1][mt][3]);
            }
            #pragma unroll
            for (int nt=0;nt<4;nt++){
                bf16x8 vf = *(const bf16x8*)(vs + pv_off[kc][nt]);
                #pragma unroll
                for (int mt=0;mt<2;mt++)
                    o_acc[mt][nt] = __builtin_amdgcn_mfma_f32_16x16x32_bf16(pu[mt].v, vf, o_acc[mt][nt], 0,0,0);
            }
        }
        cur = (cur+1==3) ? 0 : cur+1;
    }
    float rowsum[2];
    #pragma unroll
    for (int mt=0;mt<2;mt++){
        float rs = rs_part[mt];
        rs += __shfl_xor(rs, 16);
        rs += __shfl_xor(rs, 32);
        rowsum[mt] = rs;
    }
    const float gh = gate_h[h];
    float inv[2][4];
    #pragma unroll
    for (int mt=0;mt<2;mt++)
        #pragma unroll
        for (int r=0;r<4;r++)
            inv[mt][r] = gh / __shfl(rowsum[mt], (l>>4)*4 + r, 16);
    unsigned short* op = (unsigned short*)og + ((size_t)b*N_ + n0 + w*32)*C_ + h*64;
    #pragma unroll
    for (int mt=0;mt<2;mt++){
        #pragma unroll
        for (int r=0;r<4;r++){
            const int n = mt*16 + (l>>4)*4 + r;
            #pragma unroll
            for (int nt=0;nt<4;nt++)
                op[(size_t)n*C_ + nt*16 + (l&15)] = f2bf(o_acc[mt][nt][r]*inv[mt][r]);
        }
    }
}

// ---------------- launch ----------------
extern "C" void kernel_launch(void* const* d_in, const int* in_sizes, int n_in,
                              void* d_out, int out_size, void* d_ws, size_t ws_size,
                              hipStream_t stream)
{
    const float* x     = (const float*)d_in[0];
    const float* ln1g  = (const float*)d_in[1];
    const float* ln1b  = (const float*)d_in[2];
    const float* qkvw  = (const float*)d_in[3];
    const float* projw = (const float*)d_in[4];
    const float* projb = (const float*)d_in[5];
    const float* gateh = (const float*)d_in[6];
    const float* ln2g  = (const float*)d_in[7];
    const float* ln2b  = (const float*)d_in[8];
    const float* fc1w  = (const float*)d_in[9];
    const float* fc1b  = (const float*)d_in[10];
    const float* fc2w  = (const float*)d_in[11];
    const float* fc2b  = (const float*)d_in[12];
    const float* gatem = (const float*)d_in[13];
    float* out = (float*)d_out;

    char* ws = (char*)d_ws;
    __hip_bfloat16* h_buf = (__hip_bfloat16*)(ws + 0);          // 12.58MB  (h / h2)
    __hip_bfloat16* qkv   = (__hip_bfloat16*)(ws + 12582912);   // 37.75MB  (q,k,v^T)
    __hip_bfloat16* q_buf = qkv;
    __hip_bfloat16* k_buf = qkv + 6291456;
    __hip_bfloat16* vt_buf= qkv + 2*6291456;
    __hip_bfloat16* o_buf = (__hip_bfloat16*)(ws + 50331648);   // 12.58MB
    __hip_bfloat16* m_buf = (__hip_bfloat16*)(ws + 12582912);   // 50.33MB (reuses dead qkv+o)
    __hip_bfloat16* x1b   = (__hip_bfloat16*)(ws + 62914560);   // 12.58MB (bf16 residual)
    __hip_bfloat16* wqkv  = (__hip_bfloat16*)(ws + 88080384);
    __hip_bfloat16* wproj = (__hip_bfloat16*)(ws + 88965120);
    __hip_bfloat16* wfc1  = (__hip_bfloat16*)(ws + 89260032);
    __hip_bfloat16* wfc2  = (__hip_bfloat16*)(ws + 90439680);

    // LN1 + all weight converts, one launch (independent memory-bound tasks)
    ln1_cvt_kernel<<<5120, 256, 0, stream>>>(x, ln1g, ln1b, h_buf,
                                             qkvw, wqkv, 1152*384,
                                             projw, wproj, 384*384,
                                             fc1w, wfc1, 1536*384,
                                             fc2w, wfc2, 384*1536);

    // R13: exact R11 (session-best 169.3) + fast_exp2 GELU in FC1 epilogue
    gemm_wres<EPI_QKV,1152><<<1152, 256, 0, stream>>>(h_buf, wqkv, nullptr, nullptr, nullptr, qkv);
    attn_mfma<<<768, 256, 0, stream>>>(q_buf, k_buf, vt_buf, gateh, o_buf);
    gemm_wres<EPI_PROJ,384><<<384, 256, 0, stream>>>(o_buf, wproj, projb, x, nullptr, x1b);
    ln_kernel<__hip_bfloat16><<<4096, 256, 0, stream>>>(x1b, ln2g, ln2b, h_buf);
    gemm_wres4<1536><<<3072, 256, 0, stream>>>(h_buf, wfc1, fc1b, gatem, m_buf);
    gemm_wres_fc2<<<768, 256, 0, stream>>>(m_buf, wfc2, fc2b, x1b, out);
}

// Round 14
// 162.403 us; speedup vs baseline: 1.0753x; 1.0361x over previous
//
#include <hip/hip_runtime.h>
#include <hip/hip_bf16.h>
#include <cstdint>
#include <cstddef>

#define B_   16
#define N_   1024
#define C_   384
#define H_   6
#define DFF_ 1536
#define R_   16384   // B_*N_

typedef __attribute__((ext_vector_type(8))) __bf16 bf16x8;
typedef __attribute__((ext_vector_type(4))) float  f32x4;
typedef __attribute__((ext_vector_type(8))) unsigned short u16x8;
typedef __attribute__((ext_vector_type(4))) unsigned short u16x4;

__device__ __forceinline__ float bf2f(unsigned short u){
    unsigned int x = ((unsigned int)u) << 16;
    return __builtin_bit_cast(float, x);
}
__device__ __forceinline__ unsigned short f2bf(float f){
    return __builtin_bit_cast(unsigned short, __float2bfloat16(f));
}
__device__ __forceinline__ unsigned int cvt_pk_bf16(float a, float b){
    unsigned int r;
    asm("v_cvt_pk_bf16_f32 %0, %1, %2" : "=v"(r) : "v"(a), "v"(b));
    return r;   // lo = bf16(a), hi = bf16(b)
}
// raw v_exp_f32 (2^x). Args provably <= 0 -> no OCML range/denorm fixup needed.
__device__ __forceinline__ float fast_exp2(float x){
    float r;
    asm("v_exp_f32 %0, %1" : "=v"(r) : "v"(x));
    return r;
}
__device__ __forceinline__ void gload16(const void* g, void* l){
    __builtin_amdgcn_global_load_lds(
        (const __attribute__((address_space(1))) unsigned int*)g,
        (__attribute__((address_space(3))) unsigned int*)l, 16, 0, 0);
}
// exact-GELU via Abramowitz-Stegun 7.1.25 erf approx (|err| <= 2.5e-5), raw v_exp_f32
__device__ __forceinline__ float gelu_f(float u){
    float z  = fabsf(u) * 0.70710678118654752f;
    float t  = __builtin_amdgcn_rcpf(1.0f + 0.47047f*z);
    float e  = fast_exp2(-z*z*1.4426950408889634f);
    float p  = t*(0.3480242f + t*(-0.0958798f + t*0.7478556f));
    float er = 1.0f - p*e;                       // erf(z), z>=0
    return 0.5f*u*(1.0f + copysignf(er, u));
}
__device__ __forceinline__ float ldv(const float* p, size_t i){ return p[i]; }
__device__ __forceinline__ float ldv(const __hip_bfloat16* p, size_t i){ return __bfloat162float(p[i]); }

// ---------------- LN1 + all-weight fp32->bf16 convert, one launch ----------------
__global__ __launch_bounds__(256) void ln1_cvt_kernel(
    const float* __restrict__ x, const float* __restrict__ g,
    const float* __restrict__ b, __hip_bfloat16* __restrict__ out,
    const float* __restrict__ i0, __hip_bfloat16* __restrict__ o0, int n0,
    const float* __restrict__ i1, __hip_bfloat16* __restrict__ o1, int n1,
    const float* __restrict__ i2, __hip_bfloat16* __restrict__ o2, int n2,
    const float* __restrict__ i3, __hip_bfloat16* __restrict__ o3, int n3)
{
    if (blockIdx.x < 4096){
        const int lane = threadIdx.x & 63;
        const int wave = threadIdx.x >> 6;
        const int row  = blockIdx.x*4 + wave;
        const float* xr = x + (size_t)row*C_;
        float v[6];
        float s = 0.f;
        #pragma unroll
        for (int i=0;i<6;i++){ v[i] = xr[lane + i*64]; s += v[i]; }
        #pragma unroll
        for (int m=1;m<64;m<<=1) s += __shfl_xor(s, m);
        const float mean = s * (1.0f/C_);
        float sq = 0.f;
        #pragma unroll
        for (int i=0;i<6;i++){ float d = v[i]-mean; sq += d*d; }
        #pragma unroll
        for (int m=1;m<64;m<<=1) sq += __shfl_xor(sq, m);
        const float rstd = rsqrtf(sq*(1.0f/C_) + 1e-5f);
        #pragma unroll
        for (int i=0;i<6;i++){
            int c = lane + i*64;
            out[(size_t)row*C_ + c] = __float2bfloat16((v[i]-mean)*rstd*g[c] + b[c]);
        }
    } else {
        const int total = n0+n1+n2+n3;
        for (int i = (blockIdx.x-4096)*blockDim.x + threadIdx.x; i < total; i += 1024*blockDim.x){
            int k = i;
            if (k < n0){ o0[k] = __float2bfloat16(i0[k]); continue; }
            k -= n0;
            if (k < n1){ o1[k] = __float2bfloat16(i1[k]); continue; }
            k -= n1;
            if (k < n2){ o2[k] = __float2bfloat16(i2[k]); continue; }
            k -= n2;
            o3[k] = __float2bfloat16(i3[k]);
        }
    }
}

// ---------------- LayerNorm: (fp32|bf16) in -> bf16 out ----------------
template<typename T>
__global__ __launch_bounds__(256) void ln_kernel(
    const T* __restrict__ x, const float* __restrict__ g,
    const float* __restrict__ b, __hip_bfloat16* __restrict__ out)
{
    const int lane = threadIdx.x & 63;
    const int wave = threadIdx.x >> 6;
    const int row  = blockIdx.x*4 + wave;
    const T* xr = x + (size_t)row*C_;
    float v[6];
    float s = 0.f;
    #pragma unroll
    for (int i=0;i<6;i++){ v[i] = ldv(xr, lane + i*64); s += v[i]; }
    #pragma unroll
    for (int m=1;m<64;m<<=1) s += __shfl_xor(s, m);
    const float mean = s * (1.0f/C_);
    float sq = 0.f;
    #pragma unroll
    for (int i=0;i<6;i++){ float d = v[i]-mean; sq += d*d; }
    #pragma unroll
    for (int m=1;m<64;m<<=1) sq += __shfl_xor(sq, m);
    const float rstd = rsqrtf(sq*(1.0f/C_) + 1e-5f);
    #pragma unroll
    for (int i=0;i<6;i++){
        int c = lane + i*64;
        out[(size_t)row*C_ + c] = __float2bfloat16((v[i]-mean)*rstd*g[c] + b[c]);
    }
}

enum { EPI_QKV=0, EPI_PROJ=1, EPI_FC1=2, EPI_FC2=3 };

// gemm_wres: RT=2 -- B panel resident (stage-once), 4 A-bands (QKV/proj best, unchanged)
template<int EPI, int NCOLS>   // NCOLS: 1152 (QKV) / 384 (proj)
__global__ __launch_bounds__(256, 2) void gemm_wres(
    const __hip_bfloat16* __restrict__ A,    // [16384, 384]
    const __hip_bfloat16* __restrict__ Wt,   // [NCOLS, 384]
    const float* __restrict__ bias,
    const float* __restrict__ resid,
    const float* __restrict__ gate,
    __hip_bfloat16* __restrict__ outb)
{
    constexpr int NB = NCOLS/64;             // col-blocks
    constexpr int G  = 24;                   // RT=2 tiles x 12 K-steps
    __shared__ __align__(16) unsigned short As[4][128*32];   // 32KB: 4 bands, wave-private 32rx32k
    __shared__ __align__(16) unsigned short Bs[64*384];      // 48KB: whole-K weight panel
    const int t = threadIdx.x;
    const int l = t & 63;
    const int w = t >> 6;
    const int X  = blockIdx.x & 7;
    const int j8 = blockIdx.x >> 3;
    const int rb = X*8 + j8 / NB;            // row-group 0..63 (256 rows each)
    const int cb = j8 % NB;

    #pragma unroll
    for (int j=0;j<12;j++){
        const int L     = (w*12 + j)*1024 + l*16;       // linear LDS byte (gload_lds HW rule)
        const int row   = L / 768;                      // B row 0..63
        const int cbyte = L - row*768;
        const int scol  = (cbyte ^ ((row&7)<<4)) >> 1;  // inverse-swizzled source col (elems)
        gload16(Wt + (size_t)(cb*64 + row)*384 + scol, (char*)&Bs[0] + L);
    }
    const int sgcol = (((l&3) - ((l>>3)&3)) & 3) * 8;
    const size_t arow0 = (size_t)rb*256 + w*32 + (l>>2);
    auto STAGEA = [&](int g){
        const int rt = g/12, s = g - rt*12;
        #pragma unroll
        for (int c=0;c<2;c++)
            gload16(A + (arow0 + rt*128 + c*16)*384 + s*32 + sgcol,
                    (char*)&As[g&3][0] + w*2048 + c*1024 + l*16);
    };
    STAGEA(0); STAGEA(1); STAGEA(2);
    asm volatile("s_waitcnt vmcnt(6)" ::: "memory");    // 12 B loads drained; 3 bands in flight
    __builtin_amdgcn_s_barrier();                        // the ONLY barrier

    #pragma unroll
    for (int rt=0; rt<2; ++rt){
        f32x4 acc[2][4];
        #pragma unroll
        for (int i=0;i<2;i++)
            #pragma unroll
            for (int jj=0;jj<4;jj++) acc[i][jj] = (f32x4){0.f,0.f,0.f,0.f};

        #pragma unroll
        for (int s=0; s<12; ++s){
            const int g = rt*12 + s;
            if (g <= G-3)      asm volatile("s_waitcnt vmcnt(4)" ::: "memory");
            else if (g == G-2) asm volatile("s_waitcnt vmcnt(2)" ::: "memory");
            else               asm volatile("s_waitcnt vmcnt(0)" ::: "memory");
            const char* as = (const char*)&As[g&3][0] + w*2048;
            bf16x8 af[2], bw[4];
            #pragma unroll
            for (int i=0;i<2;i++){
                const int r  = i*16 + (l&15);
                const int sl = ((l>>4) + ((r>>1)&3)) & 3;
                af[i] = *(const bf16x8*)(as + r*64 + sl*16);
            }
            #pragma unroll
            for (int i=0;i<4;i++){
                const int r = i*16 + (l&15);                  // B row (output col) 0..63
                bw[i] = *(const bf16x8*)((const char*)&Bs[0] + r*768
                             + ((s*64 + (l>>4)*16) ^ ((r&7)<<4)));
            }
            #pragma unroll
            for (int mi=0;mi<2;mi++)
                #pragma unroll
                for (int ni=0;ni<4;ni++)
                    acc[mi][ni] = __builtin_amdgcn_mfma_f32_16x16x32_bf16(af[mi], bw[ni], acc[mi][ni], 0,0,0);
            asm volatile("s_waitcnt lgkmcnt(0)" ::: "memory");
            if (g+3 < G) STAGEA(g+3);
        }
        const int rowBase = rb*256 + rt*128 + w*32;
        if constexpr (EPI==EPI_QKV){
            unsigned short* ob = (unsigned short*)outb;
            #pragma unroll
            for (int ni=0; ni<4; ni++){
                const int col = cb*64 + ni*16 + (l&15);
                const int p = col/384, rem = col - p*384;
                const int hh = rem>>6, d = rem&63;
                #pragma unroll
                for (int mi=0; mi<2; mi++){
                    const int row0 = rowBase + mi*16 + (l>>4)*4;
                    const int bb = row0>>10, n = row0&1023;
                    if (p==2){
                        u16x4 pk;
                        #pragma unroll
                        for (int jj=0;jj<4;jj++) pk[jj] = f2bf(acc[mi][ni][jj]);
                        *(u16x4*)(ob + (size_t)2*6291456 + ((size_t)(bb*H_+hh)*64 + d)*1024 + n) = pk;
                    } else {
                        #pragma unroll
                        for (int jj=0;jj<4;jj++)
                            ob[(((size_t)((p*16+bb)*6+hh))<<16) + ((size_t)(n+jj)<<6) + d] = f2bf(acc[mi][ni][jj]);
                    }
                }
            }
        } else {
            #pragma unroll
            for (int ni=0; ni<4; ni++){
                const int col = cb*64 + ni*16 + (l&15);
                #pragma unroll
                for (int mi=0; mi<2; mi++){
                    #pragma unroll
                    for (int jj=0;jj<4;jj++){
                        const int row = rowBase + mi*16 + (l>>4)*4 + jj;
                        const size_t idx = (size_t)row*NCOLS + col;
                        outb[idx] = __float2bfloat16(resid[idx] + acc[mi][ni][jj] + bias[col]); // EPI_PROJ
                    }
                }
            }
        }
    }
}

// ---------------- R14: 48KB FC template -- 4-step B chunks + 4 A-bands, 3 blocks/CU ----------------
// R13 counters: FC2 = latency-bound (VALUBusy 7%, 42MB traffic = 8x above BW floor) AND
// tail-bound (grid 768 at 2 blocks/CU = 512 slots -> 1.5 generations; makespan 2x T_block).
// Shrink LDS to 48KB (As 32KB + Bs 64x128 = 16KB) -> 3 blocks/CU (verified at 49152 in R7):
//   FC2: capacity 768 = EXACTLY 1 generation (tail gone) + 12 waves/CU (+50% TLP).
//   FC1: 3072 blocks -> exactly 4 generations + 12 waves/CU.
// Chunk protocol = R11's race-fixed FC2 (verified): in-chunk s<3 no wait (bands pre-staged
// across boundary, drained by boundary vmcnt(0)); s>=3: band staged 3 steps prior, 2 newer
// bands (4 loads) behind it -> vmcnt(4), except last chunk's s=3 (no newer stages) -> vmcnt(0).
// Boundary: [all own ds_reads retired] -> barrier -> STAGEB(q+1) -> vmcnt(0) -> barrier.
// Bands are wave-private (no cross-wave hazard); B overwrite guarded by all-waves barrier.
template<int EPI, int KK, int NCOLS>   // FC1: 384,1536 ; FC2: 1536,384
__global__ __launch_bounds__(256, 3) void gemm_wres_c(
    const __hip_bfloat16* __restrict__ A,      // [16384, KK]
    const __hip_bfloat16* __restrict__ Wt,     // [NCOLS, KK]
    const float* __restrict__ bias,            // [NCOLS]
    const __hip_bfloat16* __restrict__ residb, // FC2: x1b [16384,384]
    const float* __restrict__ gate,            // FC1: gate_mlp
    __hip_bfloat16* __restrict__ outb,         // FC1 out
    float* __restrict__ outf)                  // FC2 out
{
    constexpr int NB     = NCOLS/64;           // col-blocks
    constexpr int NSTEPS = KK/32;              // 12 / 48
    constexpr int QC     = NSTEPS/4;           // 3 / 12 chunks of 4 steps
    __shared__ __align__(16) unsigned short As[4][128*32];   // 32KB: 4 wave-private bands
    __shared__ __align__(16) unsigned short Bs[64*128];      // 16KB: one 4-step B chunk
    const int t = threadIdx.x;
    const int l = t & 63;
    const int w = t >> 6;
    const int X  = blockIdx.x & 7;
    const int j8 = blockIdx.x >> 3;
    const int rb = X*16 + j8 / NB;             // row-block 0..127 (128 rows)
    const int cb = j8 % NB;

    auto STAGEB = [&](int q){                  // chunk q: K cols [q*128, q*128+127]
        #pragma unroll
        for (int j=0;j<4;j++){
            const int L     = (w*4 + j)*1024 + l*16;   // linear LDS byte
            const int row   = L / 256;                 // B row 0..63 (row stride 256B)
            const int cbyte = L - row*256;
            const int scol  = (cbyte ^ ((row&7)<<4)) >> 1;  // inverse-swizzled src col
            gload16(Wt + (size_t)(cb*64 + row)*KK + q*128 + scol, (char*)&Bs[0] + L);
        }
    };
    const int sgcol = (((l&3) - ((l>>3)&3)) & 3) * 8;
    const size_t arow0 = (size_t)rb*128 + w*32 + (l>>2);
    auto STAGEA = [&](int g){                  // global K-step g
        #pragma unroll
        for (int c=0;c<2;c++)
            gload16(A + (arow0 + c*16)*KK + g*32 + sgcol,
                    (char*)&As[g&3][0] + w*2048 + c*1024 + l*16);
    };

    STAGEB(0);
    STAGEA(0); STAGEA(1); STAGEA(2);
    asm volatile("s_waitcnt vmcnt(0)" ::: "memory");
    __builtin_amdgcn_s_barrier();
    asm volatile("" ::: "memory");

    f32x4 acc[2][4];
    #pragma unroll
    for (int i=0;i<2;i++)
        #pragma unroll
        for (int jj=0;jj<4;jj++) acc[i][jj] = (f32x4){0.f,0.f,0.f,0.f};

    for (int q=0; q<QC; ++q){
        if (q > 0){
            asm volatile("s_waitcnt vmcnt(0)" ::: "memory");   // B(q) + pre-issued bands landed
            __builtin_amdgcn_s_barrier();                       // panel ready for all waves
            asm volatile("" ::: "memory");
        }
        #pragma unroll
        for (int s=0; s<4; ++s){
            const int g = q*4 + s;
            if (s >= 3){                       // s<3: band pre-staged and drained at boundary
                if (g < NSTEPS-4) asm volatile("s_waitcnt vmcnt(4)" ::: "memory");
                else              asm volatile("s_waitcnt vmcnt(0)" ::: "memory");
            }
            const char* as = (const char*)&As[g&3][0] + w*2048;
            bf16x8 af[2], bw[4];
            #pragma unroll
            for (int i=0;i<2;i++){
                const int r  = i*16 + (l&15);          // local band row 0..31
                const int sl = ((l>>4) + ((r>>1)&3)) & 3;
                af[i] = *(const bf16x8*)(as + r*64 + sl*16);
            }
            #pragma unroll
            for (int i=0;i<4;i++){
                const int r = i*16 + (l&15);           // B row (output col) 0..63
                bw[i] = *(const bf16x8*)((const char*)&Bs[0] + r*256
                             + ((s*64 + (l>>4)*16) ^ ((r&7)<<4)));
            }
            #pragma unroll
            for (int mi=0;mi<2;mi++)
                #pragma unroll
                for (int ni=0;ni<4;ni++)
                    acc[mi][ni] = __builtin_amdgcn_mfma_f32_16x16x32_bf16(af[mi], bw[ni], acc[mi][ni], 0,0,0);
            asm volatile("s_waitcnt lgkmcnt(0)" ::: "memory");  // own ds_reads retired
            if (g+3 < NSTEPS) STAGEA(g+3);     // band buf (g+3)&3 = (g-1)&3, reads retired
        }
        if (q+1 < QC){
            __builtin_amdgcn_s_barrier();      // ALL waves done reading Bs chunk q
            asm volatile("" ::: "memory");
            STAGEB(q+1);                       // safe to overwrite shared panel
        }
    }

    // ---- epilogue (after loop) ----
    const int rowBase = rb*128 + w*32;
    if constexpr (EPI==EPI_FC1){
        #pragma unroll
        for (int ni=0; ni<4; ni++){
            const int col = cb*64 + ni*16 + (l&15);
            #pragma unroll
            for (int mi=0; mi<2; mi++){
                #pragma unroll
                for (int jj=0;jj<4;jj++){
                    const int row = rowBase + mi*16 + (l>>4)*4 + jj;
                    outb[(size_t)row*NCOLS + col] =
                        __float2bfloat16(gelu_f(acc[mi][ni][jj] + bias[col]) * gate[col]);
                }
            }
        }
    } else { // EPI_FC2: residual (bf16) + bias -> fp32 out
        const unsigned short* xb = (const unsigned short*)residb;
        #pragma unroll
        for (int ni=0; ni<4; ni++){
            const int col = cb*64 + ni*16 + (l&15);
            #pragma unroll
            for (int mi=0; mi<2; mi++){
                #pragma unroll
                for (int jj=0;jj<4;jj++){
                    const int row = rowBase + mi*16 + (l>>4)*4 + jj;
                    const size_t idx = (size_t)row*384 + col;
                    outf[idx] = bf2f(xb[idx]) + acc[mi][ni][jj] + bias[col];
                }
            }
        }
    }
}

// ---------------- MFMA flash attention, 3-buffer single-barrier pipeline ----------------
__global__ __launch_bounds__(256) void attn_mfma(
    const __hip_bfloat16* __restrict__ qg,   // [B,H,N,64]
    const __hip_bfloat16* __restrict__ kg,   // [B,H,N,64]
    const __hip_bfloat16* __restrict__ vtg,  // [B,H,64,N]
    const float* __restrict__ gate_h,
    __hip_bfloat16* __restrict__ og)         // [B,N,C]
{
    __shared__ __align__(16) unsigned short Ks [3][64*64];
    __shared__ __align__(16) unsigned short Vts[3][64*64];
    const int t = threadIdx.x;
    const int l = t & 63;
    const int w = t >> 6;
    const int X  = blockIdx.x & 7;
    const int j8 = blockIdx.x >> 3;          // 0..95
    const int bh = X*12 + (j8 >> 3);
    const int n0 = (j8 & 7) * 128;
    const int h  = bh % H_;
    const int b  = bh / H_;
    const unsigned short* qp  = (const unsigned short*)qg  + ((size_t)bh*N_ + n0 + w*32)*64;
    const unsigned short* kp  = (const unsigned short*)kg  + (size_t)bh*N_*64;
    const unsigned short* vtp = (const unsigned short*)vtg + (size_t)bh*64*N_;

    bf16x8 qf[2][2];
    #pragma unroll
    for (int mt=0;mt<2;mt++)
        #pragma unroll
        for (int dc=0;dc<2;dc++){
            u16x8 raw = *(const u16x8*)(qp + ((size_t)(mt*16 + (l&15)))*64 + dc*32 + (l>>4)*8);
            u16x8 sc;
            #pragma unroll
            for (int j=0;j<8;j++) sc[j] = f2bf(bf2f(raw[j]) * 0.1803368801111244f);
            qf[mt][dc] = __builtin_bit_cast(bf16x8, sc);
        }

    int qk_off[4][2], pv_off[2][4];
    #pragma unroll
    for (int t4=0;t4<4;t4++){
        const int i    = l & 15;
        const int row  = 8*(i>>2) + (i&3) + 4*(t4&1) + 32*(t4>>1);   // phys_k(t4, i)
        const int swzr = (row&3) | (((row>>3)&1)<<2);
        #pragma unroll
        for (int dc=0;dc<2;dc++)
            qk_off[t4][dc] = row*128 + ((dc*64 + (l>>4)*16) ^ (swzr<<4));
    }
    #pragma unroll
    for (int nt=0;nt<4;nt++){
        const int row  = nt*16 + (l&15);
        const int swzr = (row&3) | (((row>>3)&1)<<2);
        #pragma unroll
        for (int kc=0;kc<2;kc++)
            pv_off[kc][nt] = row*128 + ((kc*64 + (l>>4)*16) ^ (swzr<<4));
    }

    const int sr  = t >> 3;        // staging row 0..31 (and +32)
    const int sce = (t & 7) * 8;   // staging col (elements) before swizzle

    auto STAGE = [&](int buf, int kt){
        #pragma unroll
        for (int c=0;c<2;c++){
            const int r    = sr + c*32;
            const int swzr = (r&3) | (((r>>3)&1)<<2);
            const int col  = sce ^ (swzr<<3);           // inverse-swizzled global col
            gload16(kp  + ((size_t)(kt*64 + r))*64 + col, (char*)&Ks [buf][0] + (c*256 + t)*16);
            gload16(vtp + (size_t)r*N_ + kt*64 + col,     (char*)&Vts[buf][0] + (c*256 + t)*16);
        }
    };

    f32x4 o_acc[2][4];
    #pragma unroll
    for (int i=0;i<2;i++)
        #pragma unroll
        for (int jj=0;jj<4;jj++) o_acc[i][jj] = (f32x4){0.f,0.f,0.f,0.f};
    float rs_part[2] = {0.f, 0.f};   // per-lane partial denominators (k is lane-local)

    STAGE(0, 0);
    STAGE(1, 1);
    int cur = 0, stb = 2;
    for (int kt=0; kt<16; kt++){
        if (kt < 15) asm volatile("s_waitcnt vmcnt(4)" ::: "memory");
        else         asm volatile("s_waitcnt vmcnt(0)" ::: "memory");
        __builtin_amdgcn_s_barrier();
        asm volatile("" ::: "memory");
        if (kt < 14){
            STAGE(stb, kt+2);
            stb = (stb+1==3) ? 0 : stb+1;
        }
        const char* ks = (const char*)&Ks[cur][0];
        const char* vs = (const char*)&Vts[cur][0];

        f32x4 s_acc[4][2];
        #pragma unroll
        for (int i=0;i<4;i++)
            #pragma unroll
            for (int jj=0;jj<2;jj++) s_acc[i][jj] = (f32x4){0.f,0.f,0.f,0.f};
        #pragma unroll
        for (int t4=0;t4<4;t4++)
            #pragma unroll
            for (int dc=0;dc<2;dc++){
                bf16x8 kf = *(const bf16x8*)(ks + qk_off[t4][dc]);
                #pragma unroll
                for (int mt=0;mt<2;mt++)
                    s_acc[t4][mt] = __builtin_amdgcn_mfma_f32_16x16x32_bf16(kf, qf[mt][dc], s_acc[t4][mt], 0,0,0);
            }
        #pragma unroll
        for (int mt=0;mt<2;mt++){
            float acc_s = 0.f;
            #pragma unroll
            for (int t4=0;t4<4;t4++){
                #pragma unroll
                for (int jj=0;jj<4;jj++){
                    float e = fast_exp2(s_acc[t4][mt][jj]);
                    s_acc[t4][mt][jj] = e;
                    acc_s += e;
                }
            }
            rs_part[mt] += acc_s;
        }
        #pragma unroll
        for (int kc=0;kc<2;kc++){
            union { unsigned int u[4]; bf16x8 v; } pu[2];
            #pragma unroll
            for (int mt=0;mt<2;mt++){
                pu[mt].u[0] = cvt_pk_bf16(s_acc[2*kc  ][mt][0], s_acc[2*kc  ][mt][1]);
                pu[mt].u[1] = cvt_pk_bf16(s_acc[2*kc  ][mt][2], s_acc[2*kc  ][mt][3]);
                pu[mt].u[2] = cvt_pk_bf16(s_acc[2*kc+1][mt][0], s_acc[2*kc+1][mt][1]);
                pu[mt].u[3] = cvt_pk_bf16(s_acc[2*kc+1][mt][2], s_acc[2*kc+1][mt][3]);
            }
            #pragma unroll
            for (int nt=0;nt<4;nt++){
                bf16x8 vf = *(const bf16x8*)(vs + pv_off[kc][nt]);
                #pragma unroll
                for (int mt=0;mt<2;mt++)
                    o_acc[mt][nt] = __builtin_amdgcn_mfma_f32_16x16x32_bf16(pu[mt].v, vf, o_acc[mt][nt], 0,0,0);
            }
        }
        cur = (cur+1==3) ? 0 : cur+1;
    }
    float rowsum[2];
    #pragma unroll
    for (int mt=0;mt<2;mt++){
        float rs = rs_part[mt];
        rs += __shfl_xor(rs, 16);
        rs += __shfl_xor(rs, 32);
        rowsum[mt] = rs;
    }
    const float gh = gate_h[h];
    float inv[2][4];
    #pragma unroll
    for (int mt=0;mt<2;mt++)
        #pragma unroll
        for (int r=0;r<4;r++)
            inv[mt][r] = gh / __shfl(rowsum[mt], (l>>4)*4 + r, 16);
    unsigned short* op = (unsigned short*)og + ((size_t)b*N_ + n0 + w*32)*C_ + h*64;
    #pragma unroll
    for (int mt=0;mt<2;mt++){
        #pragma unroll
        for (int r=0;r<4;r++){
            const int n = mt*16 + (l>>4)*4 + r;
            #pragma unroll
            for (int nt=0;nt<4;nt++)
                op[(size_t)n*C_ + nt*16 + (l&15)] = f2bf(o_acc[mt][nt][r]*inv[mt][r]);
        }
    }
}

// ---------------- launch ----------------
extern "C" void kernel_launch(void* const* d_in, const int* in_sizes, int n_in,
                              void* d_out, int out_size, void* d_ws, size_t ws_size,
                              hipStream_t stream)
{
    const float* x     = (const float*)d_in[0];
    const float* ln1g  = (const float*)d_in[1];
    const float* ln1b  = (const float*)d_in[2];
    const float* qkvw  = (const float*)d_in[3];
    const float* projw = (const float*)d_in[4];
    const float* projb = (const float*)d_in[5];
    const float* gateh = (const float*)d_in[6];
    const float* ln2g  = (const float*)d_in[7];
    const float* ln2b  = (const float*)d_in[8];
    const float* fc1w  = (const float*)d_in[9];
    const float* fc1b  = (const float*)d_in[10];
    const float* fc2w  = (const float*)d_in[11];
    const float* fc2b  = (const float*)d_in[12];
    const float* gatem = (const float*)d_in[13];
    float* out = (float*)d_out;

    char* ws = (char*)d_ws;
    __hip_bfloat16* h_buf = (__hip_bfloat16*)(ws + 0);          // 12.58MB  (h / h2)
    __hip_bfloat16* qkv   = (__hip_bfloat16*)(ws + 12582912);   // 37.75MB  (q,k,v^T)
    __hip_bfloat16* q_buf = qkv;
    __hip_bfloat16* k_buf = qkv + 6291456;
    __hip_bfloat16* vt_buf= qkv + 2*6291456;
    __hip_bfloat16* o_buf = (__hip_bfloat16*)(ws + 50331648);   // 12.58MB
    __hip_bfloat16* m_buf = (__hip_bfloat16*)(ws + 12582912);   // 50.33MB (reuses dead qkv+o)
    __hip_bfloat16* x1b   = (__hip_bfloat16*)(ws + 62914560);   // 12.58MB (bf16 residual)
    __hip_bfloat16* wqkv  = (__hip_bfloat16*)(ws + 88080384);
    __hip_bfloat16* wproj = (__hip_bfloat16*)(ws + 88965120);
    __hip_bfloat16* wfc1  = (__hip_bfloat16*)(ws + 89260032);
    __hip_bfloat16* wfc2  = (__hip_bfloat16*)(ws + 90439680);

    // LN1 + all weight converts, one launch (independent memory-bound tasks)
    ln1_cvt_kernel<<<5120, 256, 0, stream>>>(x, ln1g, ln1b, h_buf,
                                             qkvw, wqkv, 1152*384,
                                             projw, wproj, 384*384,
                                             fc1w, wfc1, 1536*384,
                                             fc2w, wfc2, 384*1536);

    // R14: FC1/FC2 -> 48KB chunked template (3 blocks/CU; FC2 tail eliminated)
    gemm_wres<EPI_QKV,1152><<<1152, 256, 0, stream>>>(h_buf, wqkv, nullptr, nullptr, nullptr, qkv);
    attn_mfma<<<768, 256, 0, stream>>>(q_buf, k_buf, vt_buf, gateh, o_buf);
    gemm_wres<EPI_PROJ,384><<<384, 256, 0, stream>>>(o_buf, wproj, projb, x, nullptr, x1b);
    ln_kernel<__hip_bfloat16><<<4096, 256, 0, stream>>>(x1b, ln2g, ln2b, h_buf);
    gemm_wres_c<EPI_FC1,384,1536><<<3072, 256, 0, stream>>>(h_buf, wfc1, fc1b, nullptr, gatem, m_buf, nullptr);
    gemm_wres_c<EPI_FC2,1536,384><<<768, 256, 0, stream>>>(m_buf, wfc2, fc2b, x1b, nullptr, nullptr, out);
}